// Round 1
// baseline (10502.174 us; speedup 1.0000x reference)
//
#include <hip/hip_runtime.h>
#include <hip/hip_bf16.h>

// ---------------------------------------------------------------------------
// BiRNN: x[64,1024,512] f32 in, y[64,1024,1024]+h[2,64,512] f32 out. H=512.
// Internal compute in bf16 MFMA (threshold is 2% of ref max -> ample room).
//   Phase 0: convert x, Wih, Whh, fcW, h0 to bf16 in ws.
//   Phase 1: UH[d][t][m][n] = xb(,time-flip for bw) @ Wihb^T + (bih+bhh)
//   Phase 2: h_t = tanh(UH[d][t] + h_{t-1} @ Whhb^T) IN PLACE into UH[d][t].
//            8 workgroups (2 dir x 4 batch-groups of 16 rows), 1024 thr each.
//            Batch rows are independent -> NO cross-workgroup sync at all.
//            Columns split across the 16 waves of one block; h exchanged via
//            XOR-swizzled LDS double buffer + one __syncthreads per step.
//            Whh register-resident. U[t+1] prefetched to regs; global h store
//            delayed one step so its drain hides under MFMAs.
//   Phase 3: y = UH @ fcWb^T + fcb -> f32 d_out[m][t][d*512+n]; h_out f32.
// ws (u16 elems): UH 67108864 | Xb 33554432 | 6 x W 262144 | h0b 65536
// ---------------------------------------------------------------------------

typedef unsigned short u16;
using frag8 = __attribute__((ext_vector_type(8))) short;
using f32x4 = __attribute__((ext_vector_type(4))) float;

#define SEQ 33554432ull          // 1024*64*512 elems (one direction slab)
#define UTOT 67108864ull         // 2*SEQ

__device__ __forceinline__ float bf2f(u16 u){
  union { unsigned i; float f; } v; v.i = ((unsigned)u) << 16; return v.f;
}
__device__ __forceinline__ u16 f2bf(float f){
  union { float f; unsigned i; } v; v.f = f;
  unsigned r = v.i + 0x7FFFu + ((v.i >> 16) & 1u);
  return (u16)(r >> 16);
}
__device__ __forceinline__ float tanh_fast(float x){
  float e = __expf(2.0f * x);                 // e>=0; inf saturates fine
  return 1.0f - __fdividef(2.0f, e + 1.0f);
}
__device__ __forceinline__ void async16(void* lds, const void* g){
  __builtin_amdgcn_global_load_lds((const __attribute__((address_space(1))) void*)g,
                                   (__attribute__((address_space(3))) void*)lds,
                                   16, 0, 0);
}

// --------------------------- f32 -> bf16 convert ---------------------------
__global__ __launch_bounds__(256) void cvt_kernel(const float* __restrict__ src,
                                                  u16* __restrict__ dst, int n4)
{
  int i = blockIdx.x * 256 + threadIdx.x;
  if (i < n4) {
    float4 v = ((const float4*)src)[i];
    ushort4 o;
    o.x = f2bf(v.x); o.y = f2bf(v.y); o.z = f2bf(v.z); o.w = f2bf(v.w);
    ((ushort4*)dst)[i] = o;
  }
}

// ---------------------------------------------------------------------------
// GEMM: C[r][n] = A[r][:] @ W^T[:][n] + bias, A bf16 65536x512 per dir.
// mode 0: A row r = m*1024+t (x layout); store bf16 UH[((d*1024+tu)*64+m)*512+n],
//         tu = d ? 1023-t : t.
// mode 1: A row r' = t*64+m (UH layout); store f32 y[(m*1024+t)*1024+d*512+n].
// ---------------------------------------------------------------------------
__global__ __launch_bounds__(256, 2) void gemm_kernel(
    const u16* __restrict__ A0, const u16* __restrict__ A1,
    const u16* __restrict__ W0, const u16* __restrict__ W1,
    const float* __restrict__ ba0, const float* __restrict__ bb0,
    const float* __restrict__ ba1, const float* __restrict__ bb1,
    void* __restrict__ outv, int mode)
{
  __shared__ u16 As[2][128 * 32];
  __shared__ u16 Bs[2][128 * 32];

  int bx = blockIdx.x;
  int nt = bx & 3, mt = (bx >> 2) & 511, d = bx >> 11;
  const u16* A   = d ? A1 : A0;
  const u16* W   = d ? W1 : W0;
  const float* ba = d ? ba1 : ba0;
  const float* bb = d ? bb1 : bb0;
  int rbase = mt * 128, nbase = nt * 128;

  int tid = threadIdx.x, w = tid >> 6, l = tid & 63;
  int lr = l & 15, lq = l >> 4;
  int crow = l >> 2;           // 0..15 within a 16-row chunk
  int koff = (l & 3) * 8;      // elems within the 32-k row
  int m0 = (w >> 1) * 64, n0 = (w & 1) * 64;

  f32x4 acc[4][4] = {};

  auto stage = [&](int buf, int kc) {
    #pragma unroll
    for (int j = 0; j < 2; ++j) {
      int c = w * 2 + j;                       // 0..7, wave-uniform
      const u16* ga = A + (size_t)(rbase + c * 16 + crow) * 512 + kc * 32 + koff;
      async16(&As[buf][c * 512], ga);
      const u16* gb = W + (size_t)(nbase + c * 16 + crow) * 512 + kc * 32 + koff;
      async16(&Bs[buf][c * 512], gb);
    }
  };

  stage(0, 0);
  __syncthreads();
  for (int kc = 0; kc < 16; ++kc) {
    int buf = kc & 1;
    if (kc < 15) stage(buf ^ 1, kc + 1);
    frag8 af[4], bfv[4];
    #pragma unroll
    for (int i = 0; i < 4; ++i) {
      af[i]  = *(const frag8*)&As[buf][(m0 + i * 16 + lr) * 32 + lq * 8];
      bfv[i] = *(const frag8*)&Bs[buf][(n0 + i * 16 + lr) * 32 + lq * 8];
    }
    #pragma unroll
    for (int mi = 0; mi < 4; ++mi)
      #pragma unroll
      for (int ni = 0; ni < 4; ++ni)
        acc[mi][ni] = __builtin_amdgcn_mfma_f32_16x16x32_bf16(af[mi], bfv[ni], acc[mi][ni], 0, 0, 0);
    __syncthreads();
  }

  // epilogue: D layout row=(lq*4+rr), col=lr
  #pragma unroll
  for (int ni = 0; ni < 4; ++ni) {
    int n = nbase + n0 + ni * 16 + lr;
    float bias = ba[n] + (bb ? bb[n] : 0.0f);
    #pragma unroll
    for (int mi = 0; mi < 4; ++mi) {
      #pragma unroll
      for (int rr = 0; rr < 4; ++rr) {
        int r = rbase + m0 + mi * 16 + lq * 4 + rr;
        float v = acc[mi][ni][rr] + bias;
        if (mode == 0) {
          int m = r >> 10, t = r & 1023;
          int tu = d ? (1023 - t) : t;
          ((u16*)outv)[((size_t)((d * 1024 + tu) * 64 + m)) * 512 + n] = f2bf(v);
        } else {
          int t = r >> 6, m = r & 63;
          ((float*)outv)[((size_t)m * 1024 + t) * 1024 + d * 512 + n] = v;
        }
      }
    }
  }
}

// ---------------------------------------------------------------------------
// Recurrence: 8 blocks x 1024 threads (16 waves, one CU each).
// Block b: d = b>>2 (direction), g = b&3 (batch rows g*16..g*16+15).
// Wave w owns output cols w*32..w*32+31; Whhb[32x512] slice in VGPRs.
// h double-buffered in LDS, XOR-swizzled (byte ^= (row&7)<<4) so the
// 1KB-row-stride ds_read_b128 A-frag reads don't bank-conflict.
// U[t] prefetched to registers one step ahead; h_t global store (into the
// same UH slots, for phase 3) delayed one step so its drain hides under
// the next step's MFMAs. One __syncthreads per step; no atomics.
// ---------------------------------------------------------------------------
__global__ __launch_bounds__(1024) void rnn_kernel(
    const u16* __restrict__ h0b,
    const u16* __restrict__ Whh0, const u16* __restrict__ Whh1,
    u16* __restrict__ UH, float* __restrict__ tail)
{
  __shared__ u16 hb[2][16 * 512];          // 32 KiB, swizzled

  int b = blockIdx.x;
  int d = b >> 2, g = b & 3;
  int tid = threadIdx.x;
  int w = tid >> 6, l = tid & 63;
  int lr = l & 15, lq = l >> 4;

  const u16* Whh = d ? Whh1 : Whh0;

  // B-frags: n = w*32 + tl*16 + lr ; k = ks*32 + lq*8  (B[k][n] = Whh[n][k])
  frag8 Bf[2][16];
  #pragma unroll
  for (int tl = 0; tl < 2; ++tl)
    #pragma unroll
    for (int ks = 0; ks < 16; ++ks)
      Bf[tl][ks] = *(const frag8*)(Whh + (size_t)(w * 32 + tl * 16 + lr) * 512 + ks * 32 + lq * 8);

  // stage h0 -> hb[1] (t=0 reads buffer 1), applying the XOR swizzle
  {
    int row = tid >> 6;                    // 0..15
    int cb  = tid & 63;                    // 16B block within row
    const u16* src = h0b + (size_t)(d * 64 + g * 16) * 512 + (size_t)tid * 8;
    int dst = row * 1024 + ((cb * 16) ^ ((row & 7) << 4));
    *(frag8*)((char*)(&hb[1][0]) + dst) = *(const frag8*)src;
  }

  // per-lane element offsets within one t-slab (same for U read & h write)
  u16* Uslab = UH + (size_t)d * SEQ;       // + t*32768 per step
  int eoff[2][4];
  #pragma unroll
  for (int tl = 0; tl < 2; ++tl)
    #pragma unroll
    for (int rr = 0; rr < 4; ++rr)
      eoff[tl][rr] = (g * 16 + lq * 4 + rr) * 512 + w * 32 + tl * 16 + lr;

  // prefetch U[0] to registers
  u16 pre[2][4];
  #pragma unroll
  for (int tl = 0; tl < 2; ++tl)
    #pragma unroll
    for (int rr = 0; rr < 4; ++rr)
      pre[tl][rr] = Uslab[eoff[tl][rr]];

  u16 sv[2][4];                            // h_{t-1} pending global store
  __syncthreads();

  for (int t = 0; t < 1024; ++t) {
    int cur = t & 1, prv = cur ^ 1;

    // 1) delayed global store of h_{t-1} (drains under this step's MFMAs)
    if (t > 0) {
      u16* sp = Uslab + (size_t)(t - 1) * 32768;
      #pragma unroll
      for (int tl = 0; tl < 2; ++tl)
        #pragma unroll
        for (int rr = 0; rr < 4; ++rr)
          sp[eoff[tl][rr]] = sv[tl][rr];
    }

    // 2) acc init from prefetched U[t]
    f32x4 c0, c1;
    #pragma unroll
    for (int rr = 0; rr < 4; ++rr) { c0[rr] = bf2f(pre[0][rr]); c1[rr] = bf2f(pre[1][rr]); }

    // 3) prefetch U[t+1] (lane-private; same addresses this lane overwrites
    //    with h_{t+1} next step, so ordering is by per-lane data dependency)
    if (t < 1023) {
      const u16* up = Uslab + (size_t)(t + 1) * 32768;
      #pragma unroll
      for (int tl = 0; tl < 2; ++tl)
        #pragma unroll
        for (int rr = 0; rr < 4; ++rr)
          pre[tl][rr] = up[eoff[tl][rr]];
    }

    // 4) MFMAs: A from swizzled LDS h_{t-1}, m = lr, k = ks*32 + lq*8
    const char* hbase = (const char*)(&hb[prv][0]);
    #pragma unroll
    for (int ks = 0; ks < 16; ++ks) {
      frag8 a = *(const frag8*)(hbase + (lr * 1024 + ((ks * 64 + lq * 16) ^ ((lr & 7) << 4))));
      c0 = __builtin_amdgcn_mfma_f32_16x16x32_bf16(a, Bf[0][ks], c0, 0, 0, 0);
      c1 = __builtin_amdgcn_mfma_f32_16x16x32_bf16(a, Bf[1][ks], c1, 0, 0, 0);
    }

    // 5) tanh + swizzled LDS write + stash for delayed global store
    char* obase = (char*)(&hb[cur][0]);
    #pragma unroll
    for (int rr = 0; rr < 4; ++rr) {
      int row = lq * 4 + rr;
      float v0 = tanh_fast(c0[rr]);
      float v1 = tanh_fast(c1[rr]);
      u16 b0 = f2bf(v0), b1 = f2bf(v1);
      int col0 = w * 32 + lr, col1 = col0 + 16;
      *(u16*)(obase + (row * 1024 + ((col0 * 2) ^ ((row & 7) << 4)))) = b0;
      *(u16*)(obase + (row * 1024 + ((col1 * 2) ^ ((row & 7) << 4)))) = b1;
      sv[0][rr] = b0; sv[1][rr] = b1;
      if (t == 1023) {
        size_t tb = (size_t)(d * 64 + g * 16 + row) * 512 + col0;
        tail[tb]      = v0;
        tail[tb + 16] = v1;
      }
    }
    __syncthreads();
  }

  // final global store of h_1023
  {
    u16* sp = Uslab + (size_t)1023 * 32768;
    #pragma unroll
    for (int tl = 0; tl < 2; ++tl)
      #pragma unroll
      for (int rr = 0; rr < 4; ++rr)
        sp[eoff[tl][rr]] = sv[tl][rr];
  }
}

// ---------------------------------------------------------------------------
extern "C" void kernel_launch(void* const* d_in, const int* in_sizes, int n_in,
                              void* d_out, int out_size, void* d_ws, size_t ws_size,
                              hipStream_t stream)
{
  const float* x     = (const float*)d_in[0];
  const float* h0    = (const float*)d_in[1];
  const float* fwWih = (const float*)d_in[2];
  const float* fwWhh = (const float*)d_in[3];
  const float* fwbih = (const float*)d_in[4];
  const float* fwbhh = (const float*)d_in[5];
  const float* fwfcW = (const float*)d_in[6];
  const float* fwfcb = (const float*)d_in[7];
  const float* bwWih = (const float*)d_in[8];
  const float* bwWhh = (const float*)d_in[9];
  const float* bwbih = (const float*)d_in[10];
  const float* bwbhh = (const float*)d_in[11];
  const float* bwfcW = (const float*)d_in[12];
  const float* bwfcb = (const float*)d_in[13];

  float* out = (float*)d_out;

  u16* UH    = (u16*)d_ws;
  u16* Xb    = UH + UTOT;
  u16* Wihb0 = Xb + SEQ;            // x is 33554432 elems
  u16* Wihb1 = Wihb0 + 262144;
  u16* Whhb0 = Wihb1 + 262144;
  u16* Whhb1 = Whhb0 + 262144;
  u16* fcWb0 = Whhb1 + 262144;
  u16* fcWb1 = fcWb0 + 262144;
  u16* h0b   = fcWb1 + 262144;

  // Phase 0: f32 -> bf16 conversions
  cvt_kernel<<<32768, 256, 0, stream>>>(x, Xb, 8388608);
  cvt_kernel<<<256, 256, 0, stream>>>(fwWih, Wihb0, 65536);
  cvt_kernel<<<256, 256, 0, stream>>>(bwWih, Wihb1, 65536);
  cvt_kernel<<<256, 256, 0, stream>>>(fwWhh, Whhb0, 65536);
  cvt_kernel<<<256, 256, 0, stream>>>(bwWhh, Whhb1, 65536);
  cvt_kernel<<<256, 256, 0, stream>>>(fwfcW, fcWb0, 65536);
  cvt_kernel<<<256, 256, 0, stream>>>(bwfcW, fcWb1, 65536);
  cvt_kernel<<<64, 256, 0, stream>>>(h0, h0b, 16384);

  // Phase 1: UH = xb @ Wihb^T + (bih+bhh), both dirs (bw time-flip at store)
  gemm_kernel<<<4096, 256, 0, stream>>>(Xb, Xb, Wihb0, Wihb1,
                                        fwbih, fwbhh, bwbih, bwbhh, UH, 0);

  // Phase 2: recurrence, batch-independent -> 8 self-contained workgroups
  rnn_kernel<<<8, 1024, 0, stream>>>(h0b, Whhb0, Whhb1, UH, out + 67108864ull);

  // Phase 3: y = UH @ fcWb^T + fcb  (f32 output)
  gemm_kernel<<<4096, 256, 0, stream>>>(UH, UH + SEQ, fcWb0, fcWb1,
                                        fwfcb, nullptr, bwfcb, nullptr, out, 1);
}

// Round 2
// 7145.131 us; speedup vs baseline: 1.4698x; 1.4698x over previous
//
#include <hip/hip_runtime.h>
#include <hip/hip_bf16.h>

// ---------------------------------------------------------------------------
// BiRNN: x[64,1024,512] f32 in, y[64,1024,1024]+h[2,64,512] f32 out. H=512.
// Internal compute in bf16 MFMA (threshold is 2% of ref max -> ample room).
//   Phase 0: convert x, Wih, Whh, fcW, h0 to bf16 in ws.
//   Phase 1: UH[d][t][m][n] = xb(,time-flip for bw) @ Wihb^T + (bih+bhh)
//   Phase 2: h_t = tanh(UH[d][t] + h_{t-1} @ Whhb^T) IN PLACE into UH[d][t].
//            128 persistent single-wave blocks (1 wave/CU -> Whh slice has
//            full register budget; Whh CANNOT fit one CU: 512KB = whole RF).
//            Sync redesign vs r0: per-wave release-FLAGS in separate 128B
//            lines (parallel stores) + lane-parallel flag poll + one acquire
//            fence -- replaces 16 serialized agent-scope RMWs on one line.
//   Phase 3: y = UH @ fcWb^T + fcb -> f32 d_out[m][t][d*512+n]; h_out f32.
// ws (u16 elems): UH 67108864 | Xb 33554432 | 6 x W 262144 | h0b 65536
// flags reuse the Xb region (dead after phase-1 gemm; memset'd in-stream).
// ---------------------------------------------------------------------------

typedef unsigned short u16;
using frag8 = __attribute__((ext_vector_type(8))) short;
using f32x4 = __attribute__((ext_vector_type(4))) float;

#define SEQ 33554432ull          // 1024*64*512 elems (one direction slab)
#define UTOT 67108864ull         // 2*SEQ

__device__ __forceinline__ float bf2f(u16 u){
  union { unsigned i; float f; } v; v.i = ((unsigned)u) << 16; return v.f;
}
__device__ __forceinline__ u16 f2bf(float f){
  union { float f; unsigned i; } v; v.f = f;
  unsigned r = v.i + 0x7FFFu + ((v.i >> 16) & 1u);
  return (u16)(r >> 16);
}
__device__ __forceinline__ float tanh_fast(float x){
  float e = __expf(2.0f * x);                 // e>=0; inf saturates fine
  return 1.0f - __fdividef(2.0f, e + 1.0f);
}
__device__ __forceinline__ void async16(void* lds, const void* g){
  __builtin_amdgcn_global_load_lds((const __attribute__((address_space(1))) void*)g,
                                   (__attribute__((address_space(3))) void*)lds,
                                   16, 0, 0);
}

// --------------------------- f32 -> bf16 convert ---------------------------
__global__ __launch_bounds__(256) void cvt_kernel(const float* __restrict__ src,
                                                  u16* __restrict__ dst, int n4)
{
  int i = blockIdx.x * 256 + threadIdx.x;
  if (i < n4) {
    float4 v = ((const float4*)src)[i];
    ushort4 o;
    o.x = f2bf(v.x); o.y = f2bf(v.y); o.z = f2bf(v.z); o.w = f2bf(v.w);
    ((ushort4*)dst)[i] = o;
  }
}

// ---------------------------------------------------------------------------
// GEMM: C[r][n] = A[r][:] @ W^T[:][n] + bias, A bf16 65536x512 per dir.
// mode 0: A row r = m*1024+t (x layout); store bf16 UH[((d*1024+tu)*64+m)*512+n],
//         tu = d ? 1023-t : t.
// mode 1: A row r' = t*64+m (UH layout); store f32 y[(m*1024+t)*1024+d*512+n].
// ---------------------------------------------------------------------------
__global__ __launch_bounds__(256, 2) void gemm_kernel(
    const u16* __restrict__ A0, const u16* __restrict__ A1,
    const u16* __restrict__ W0, const u16* __restrict__ W1,
    const float* __restrict__ ba0, const float* __restrict__ bb0,
    const float* __restrict__ ba1, const float* __restrict__ bb1,
    void* __restrict__ outv, int mode)
{
  __shared__ u16 As[2][128 * 32];
  __shared__ u16 Bs[2][128 * 32];

  int bx = blockIdx.x;
  int nt = bx & 3, mt = (bx >> 2) & 511, d = bx >> 11;
  const u16* A   = d ? A1 : A0;
  const u16* W   = d ? W1 : W0;
  const float* ba = d ? ba1 : ba0;
  const float* bb = d ? bb1 : bb0;
  int rbase = mt * 128, nbase = nt * 128;

  int tid = threadIdx.x, w = tid >> 6, l = tid & 63;
  int lr = l & 15, lq = l >> 4;
  int crow = l >> 2;           // 0..15 within a 16-row chunk
  int koff = (l & 3) * 8;      // elems within the 32-k row
  int m0 = (w >> 1) * 64, n0 = (w & 1) * 64;

  f32x4 acc[4][4] = {};

  auto stage = [&](int buf, int kc) {
    #pragma unroll
    for (int j = 0; j < 2; ++j) {
      int c = w * 2 + j;                       // 0..7, wave-uniform
      const u16* ga = A + (size_t)(rbase + c * 16 + crow) * 512 + kc * 32 + koff;
      async16(&As[buf][c * 512], ga);
      const u16* gb = W + (size_t)(nbase + c * 16 + crow) * 512 + kc * 32 + koff;
      async16(&Bs[buf][c * 512], gb);
    }
  };

  stage(0, 0);
  __syncthreads();
  for (int kc = 0; kc < 16; ++kc) {
    int buf = kc & 1;
    if (kc < 15) stage(buf ^ 1, kc + 1);
    frag8 af[4], bfv[4];
    #pragma unroll
    for (int i = 0; i < 4; ++i) {
      af[i]  = *(const frag8*)&As[buf][(m0 + i * 16 + lr) * 32 + lq * 8];
      bfv[i] = *(const frag8*)&Bs[buf][(n0 + i * 16 + lr) * 32 + lq * 8];
    }
    #pragma unroll
    for (int mi = 0; mi < 4; ++mi)
      #pragma unroll
      for (int ni = 0; ni < 4; ++ni)
        acc[mi][ni] = __builtin_amdgcn_mfma_f32_16x16x32_bf16(af[mi], bfv[ni], acc[mi][ni], 0, 0, 0);
    __syncthreads();
  }

  // epilogue: D layout row=(lq*4+rr), col=lr
  #pragma unroll
  for (int ni = 0; ni < 4; ++ni) {
    int n = nbase + n0 + ni * 16 + lr;
    float bias = ba[n] + (bb ? bb[n] : 0.0f);
    #pragma unroll
    for (int mi = 0; mi < 4; ++mi) {
      #pragma unroll
      for (int rr = 0; rr < 4; ++rr) {
        int r = rbase + m0 + mi * 16 + lq * 4 + rr;
        float v = acc[mi][ni][rr] + bias;
        if (mode == 0) {
          int m = r >> 10, t = r & 1023;
          int tu = d ? (1023 - t) : t;
          ((u16*)outv)[((size_t)((d * 1024 + tu) * 64 + m)) * 512 + n] = f2bf(v);
        } else {
          int t = r >> 6, m = r & 63;
          ((float*)outv)[((size_t)m * 1024 + t) * 1024 + d * 512 + n] = v;
        }
      }
    }
  }
}

// ---------------------------------------------------------------------------
// Recurrence: 128 blocks x 64 threads (1 wave each; trivially co-resident).
// bid = p*8 + G; G=(d*4+g) is the sync group (16 waves, one per 32-col chunk
// p). Whhb[32x512] slice per wave. UH[d][t][m][n]: read own U slice, then
// overwrite the same elements with h_t.
// Sync: per-wave flag word at flags[(G*16+p)*32] (128B spacing).
//   writer: h stores -> fence(release,agent) -> relaxed flag store = t+1.
//   reader: lanes 0..15 each poll one flag (one lane-parallel load/round),
//           __all(flag >= t) -> fence(acquire,agent) -> read h_{t-1}.
// No RMW, no shared cacheline: the 16 release stores proceed in parallel
// instead of serializing ~16 cross-XCD atomic round-trips per step.
// ---------------------------------------------------------------------------
__global__ __launch_bounds__(64, 1) void rnn_kernel(
    const u16* __restrict__ h0b,
    const u16* __restrict__ Whh0, const u16* __restrict__ Whh1,
    u16* __restrict__ UH, float* __restrict__ tail, int* __restrict__ flags)
{
  int bid = blockIdx.x;
  int G = bid & 7;
  int p = bid >> 3;
  int d = G >> 2, g = G & 3;
  int l = threadIdx.x;
  int lr = l & 15, lq = l >> 4;

  const u16* Whh = d ? Whh1 : Whh0;

  // B-frags: n = p*32 + tl*16 + lr ; k = ks*32 + lq*8  (B[k][n] = Whh[n][k])
  frag8 Bf[2][16];
  #pragma unroll
  for (int tl = 0; tl < 2; ++tl)
    #pragma unroll
    for (int ks = 0; ks < 16; ++ks)
      Bf[tl][ks] = *(const frag8*)(Whh + (size_t)(p * 32 + tl * 16 + lr) * 512 + ks * 32 + lq * 8);

  int* myflag = flags + (G * 16 + p) * 32;          // this wave's flag line
  const int* pollp = flags + (G * 16 + (l & 15)) * 32; // lane i polls flag i

  // A-frag (h_{t-1}): m = lr (batch row within group), k = ks*32 + lq*8
  const u16* h0p = h0b + (size_t)(d * 64 + g * 16 + lr) * 512 + lq * 8;
  const u16* HbA = UH + ((size_t)d * 65536 + (size_t)(g * 16 + lr)) * 512 + lq * 8; // + t*32768
  // C rows: m = g*16 + lq*4 + rr; cols n = p*32 + tl*16 + lr
  u16* Up = UH + ((size_t)d * 65536 + (size_t)(g * 16 + lq * 4)) * 512 + p * 32 + lr; // + t*32768

  for (int t = 0; t < 1024; ++t) {
    // Prefetch own U slice (these elems are only ever touched by this wave
    // at step t, so reading before the wait is race-free).
    float uv[2][4];
    {
      const u16* up = Up + (size_t)t * 32768;
      #pragma unroll
      for (int tl = 0; tl < 2; ++tl)
        #pragma unroll
        for (int rr = 0; rr < 4; ++rr)
          uv[tl][rr] = bf2f(up[(size_t)rr * 512 + tl * 16]);
    }
    if (t > 0) {
      // lane-parallel poll: one global load covers all 16 flags per round
      for (;;) {
        int v = __hip_atomic_load(pollp, __ATOMIC_RELAXED, __HIP_MEMORY_SCOPE_AGENT);
        if (__all(v >= t)) break;
        __builtin_amdgcn_s_sleep(1);
      }
      __builtin_amdgcn_fence(__ATOMIC_ACQUIRE, "agent");
    }
    f32x4 c0, c1;
    #pragma unroll
    for (int rr = 0; rr < 4; ++rr) { c0[rr] = uv[0][rr]; c1[rr] = uv[1][rr]; }

    const u16* ap = (t == 0) ? h0p : (HbA + (size_t)(t - 1) * 32768);
    #pragma unroll
    for (int ks = 0; ks < 16; ++ks) {
      frag8 a = *(const frag8*)(ap + ks * 32);
      c0 = __builtin_amdgcn_mfma_f32_16x16x32_bf16(a, Bf[0][ks], c0, 0, 0, 0);
      c1 = __builtin_amdgcn_mfma_f32_16x16x32_bf16(a, Bf[1][ks], c1, 0, 0, 0);
    }

    u16* sp = Up + (size_t)t * 32768;
    #pragma unroll
    for (int rr = 0; rr < 4; ++rr) {
      float v0 = tanh_fast(c0[rr]);
      float v1 = tanh_fast(c1[rr]);
      sp[(size_t)rr * 512]      = f2bf(v0);
      sp[(size_t)rr * 512 + 16] = f2bf(v1);
      if (t == 1023) {
        size_t tb = (size_t)(d * 64 + g * 16 + lq * 4 + rr) * 512 + p * 32 + lr;
        tail[tb]      = v0;
        tail[tb + 16] = v1;
      }
    }
    // release: make h_t stores visible at agent scope, then flag (no RMW)
    __builtin_amdgcn_fence(__ATOMIC_RELEASE, "agent");
    if (l == 0)
      __hip_atomic_store(myflag, t + 1, __ATOMIC_RELAXED, __HIP_MEMORY_SCOPE_AGENT);
  }
}

// ---------------------------------------------------------------------------
extern "C" void kernel_launch(void* const* d_in, const int* in_sizes, int n_in,
                              void* d_out, int out_size, void* d_ws, size_t ws_size,
                              hipStream_t stream)
{
  const float* x     = (const float*)d_in[0];
  const float* h0    = (const float*)d_in[1];
  const float* fwWih = (const float*)d_in[2];
  const float* fwWhh = (const float*)d_in[3];
  const float* fwbih = (const float*)d_in[4];
  const float* fwbhh = (const float*)d_in[5];
  const float* fwfcW = (const float*)d_in[6];
  const float* fwfcb = (const float*)d_in[7];
  const float* bwWih = (const float*)d_in[8];
  const float* bwWhh = (const float*)d_in[9];
  const float* bwbih = (const float*)d_in[10];
  const float* bwbhh = (const float*)d_in[11];
  const float* bwfcW = (const float*)d_in[12];
  const float* bwfcb = (const float*)d_in[13];

  float* out = (float*)d_out;

  u16* UH    = (u16*)d_ws;
  u16* Xb    = UH + UTOT;
  u16* Wihb0 = Xb + SEQ;            // x is 33554432 elems
  u16* Wihb1 = Wihb0 + 262144;
  u16* Whhb0 = Wihb1 + 262144;
  u16* Whhb1 = Whhb0 + 262144;
  u16* fcWb0 = Whhb1 + 262144;
  u16* fcWb1 = fcWb0 + 262144;
  u16* h0b   = fcWb1 + 262144;

  // flags live in the Xb region: Xb is dead once phase-1 gemm has read it,
  // and the memset below is stream-ordered after that gemm.
  int* flags = (int*)Xb;            // 8 groups x 16 waves x 128B = 16 KiB

  // Phase 0: f32 -> bf16 conversions
  cvt_kernel<<<32768, 256, 0, stream>>>(x, Xb, 8388608);
  cvt_kernel<<<256, 256, 0, stream>>>(fwWih, Wihb0, 65536);
  cvt_kernel<<<256, 256, 0, stream>>>(bwWih, Wihb1, 65536);
  cvt_kernel<<<256, 256, 0, stream>>>(fwWhh, Whhb0, 65536);
  cvt_kernel<<<256, 256, 0, stream>>>(bwWhh, Whhb1, 65536);
  cvt_kernel<<<256, 256, 0, stream>>>(fwfcW, fcWb0, 65536);
  cvt_kernel<<<256, 256, 0, stream>>>(bwfcW, fcWb1, 65536);
  cvt_kernel<<<64, 256, 0, stream>>>(h0, h0b, 16384);

  // Phase 1: UH = xb @ Wihb^T + (bih+bhh), both dirs (bw time-flip at store)
  gemm_kernel<<<4096, 256, 0, stream>>>(Xb, Xb, Wihb0, Wihb1,
                                        fwbih, fwbhh, bwbih, bwbhh, UH, 0);

  // zero flags (after phase-1 gemm is done with Xb)
  hipMemsetAsync(flags, 0, 16384, stream);

  // Phase 2: recurrence, h stored in place into UH
  rnn_kernel<<<128, 64, 0, stream>>>(h0b, Whhb0, Whhb1, UH,
                                     out + 67108864ull, flags);

  // Phase 3: y = UH @ fcWb^T + fcb  (f32 output)
  gemm_kernel<<<4096, 256, 0, stream>>>(UH, UH + SEQ, fcWb0, fcWb1,
                                        fwfcb, nullptr, bwfcb, nullptr, out, 1);
}

// Round 5
// 3639.200 us; speedup vs baseline: 2.8858x; 1.9634x over previous
//
#include <hip/hip_runtime.h>
#include <hip/hip_bf16.h>

// ---------------------------------------------------------------------------
// BiRNN: x[64,1024,512] f32 in, y[64,1024,1024]+h[2,64,512] f32 out. H=512.
// Internal compute in bf16 MFMA.
//   Phase 0: convert x, Wih, Whh, fcW, h0 to bf16 in ws.
//   Phase 1: UH[d][t][m][n] = xb(,time-flip for bw) @ Wihb^T + (bih+bhh)
//   Phase 2: h_t = tanh(UH[d][t] + h_{t-1} @ Whhb^T) IN PLACE into UH[d][t].
//            128 persistent single-wave blocks. Sync design (r4): ZERO
//            fences, zero RMWs, zero hand-rolled cache bits. Every racing
//            access is a RELAXED AGENT-scope atomic (compiler emits the
//            correct coherence bits: performed at the coherence point,
//            never served from a stale local cache):
//              - h_t published as packed bf16x2 u32 atomic stores (in place)
//              - release ordering = one bare s_waitcnt vmcnt(0) (store-ack)
//                before a relaxed atomic flag store
//              - readers poll relaxed atomic flags (lane i watches flag i),
//                then read h_{t-1} as relaxed atomic u64 loads
//            No buffer_inv / buffer_wbl2 per step anywhere.
//   Phase 3: y = UH @ fcWb^T + fcb -> f32 d_out[m][t][d*512+n]; h_out f32.
// ws (u16 elems): UH 67108864 | Xb 33554432 | 6 x W 262144 | h0b 65536
// flags reuse the Xb region (dead after phase-1 gemm; memset'd in-stream).
// ---------------------------------------------------------------------------

typedef unsigned short u16;
typedef unsigned int u32;
typedef unsigned long long u64;
using frag8 = __attribute__((ext_vector_type(8))) short;
using f32x4 = __attribute__((ext_vector_type(4))) float;

#define SEQ 33554432ull          // 1024*64*512 elems (one direction slab)
#define UTOT 67108864ull         // 2*SEQ

__device__ __forceinline__ float bf2f(u16 u){
  union { unsigned i; float f; } v; v.i = ((unsigned)u) << 16; return v.f;
}
__device__ __forceinline__ u16 f2bf(float f){
  union { float f; unsigned i; } v; v.f = f;
  unsigned r = v.i + 0x7FFFu + ((v.i >> 16) & 1u);
  return (u16)(r >> 16);
}
__device__ __forceinline__ float tanh_fast(float x){
  float e = __expf(2.0f * x);                 // e>=0; inf saturates fine
  return 1.0f - __fdividef(2.0f, e + 1.0f);
}
__device__ __forceinline__ void async16(void* lds, const void* g){
  __builtin_amdgcn_global_load_lds((const __attribute__((address_space(1))) void*)g,
                                   (__attribute__((address_space(3))) void*)lds,
                                   16, 0, 0);
}

// --------------------------- f32 -> bf16 convert ---------------------------
__global__ __launch_bounds__(256) void cvt_kernel(const float* __restrict__ src,
                                                  u16* __restrict__ dst, int n4)
{
  int i = blockIdx.x * 256 + threadIdx.x;
  if (i < n4) {
    float4 v = ((const float4*)src)[i];
    ushort4 o;
    o.x = f2bf(v.x); o.y = f2bf(v.y); o.z = f2bf(v.z); o.w = f2bf(v.w);
    ((ushort4*)dst)[i] = o;
  }
}

// ---------------------------------------------------------------------------
// GEMM: C[r][n] = A[r][:] @ W^T[:][n] + bias, A bf16 65536x512 per dir.
// mode 0: A row r = m*1024+t (x layout); store bf16 UH[((d*1024+tu)*64+m)*512+n],
//         tu = d ? 1023-t : t.
// mode 1: A row r' = t*64+m (UH layout); store f32 y[(m*1024+t)*1024+d*512+n].
// ---------------------------------------------------------------------------
__global__ __launch_bounds__(256, 2) void gemm_kernel(
    const u16* __restrict__ A0, const u16* __restrict__ A1,
    const u16* __restrict__ W0, const u16* __restrict__ W1,
    const float* __restrict__ ba0, const float* __restrict__ bb0,
    const float* __restrict__ ba1, const float* __restrict__ bb1,
    void* __restrict__ outv, int mode)
{
  __shared__ u16 As[2][128 * 32];
  __shared__ u16 Bs[2][128 * 32];

  int bx = blockIdx.x;
  int nt = bx & 3, mt = (bx >> 2) & 511, d = bx >> 11;
  const u16* A   = d ? A1 : A0;
  const u16* W   = d ? W1 : W0;
  const float* ba = d ? ba1 : ba0;
  const float* bb = d ? bb1 : bb0;
  int rbase = mt * 128, nbase = nt * 128;

  int tid = threadIdx.x, w = tid >> 6, l = tid & 63;
  int lr = l & 15, lq = l >> 4;
  int crow = l >> 2;           // 0..15 within a 16-row chunk
  int koff = (l & 3) * 8;      // elems within the 32-k row
  int m0 = (w >> 1) * 64, n0 = (w & 1) * 64;

  f32x4 acc[4][4] = {};

  auto stage = [&](int buf, int kc) {
    #pragma unroll
    for (int j = 0; j < 2; ++j) {
      int c = w * 2 + j;                       // 0..7, wave-uniform
      const u16* ga = A + (size_t)(rbase + c * 16 + crow) * 512 + kc * 32 + koff;
      async16(&As[buf][c * 512], ga);
      const u16* gb = W + (size_t)(nbase + c * 16 + crow) * 512 + kc * 32 + koff;
      async16(&Bs[buf][c * 512], gb);
    }
  };

  stage(0, 0);
  __syncthreads();
  for (int kc = 0; kc < 16; ++kc) {
    int buf = kc & 1;
    if (kc < 15) stage(buf ^ 1, kc + 1);
    frag8 af[4], bfv[4];
    #pragma unroll
    for (int i = 0; i < 4; ++i) {
      af[i]  = *(const frag8*)&As[buf][(m0 + i * 16 + lr) * 32 + lq * 8];
      bfv[i] = *(const frag8*)&Bs[buf][(n0 + i * 16 + lr) * 32 + lq * 8];
    }
    #pragma unroll
    for (int mi = 0; mi < 4; ++mi)
      #pragma unroll
      for (int ni = 0; ni < 4; ++ni)
        acc[mi][ni] = __builtin_amdgcn_mfma_f32_16x16x32_bf16(af[mi], bfv[ni], acc[mi][ni], 0, 0, 0);
    __syncthreads();
  }

  // epilogue: D layout row=(lq*4+rr), col=lr
  #pragma unroll
  for (int ni = 0; ni < 4; ++ni) {
    int n = nbase + n0 + ni * 16 + lr;
    float bias = ba[n] + (bb ? bb[n] : 0.0f);
    #pragma unroll
    for (int mi = 0; mi < 4; ++mi) {
      #pragma unroll
      for (int rr = 0; rr < 4; ++rr) {
        int r = rbase + m0 + mi * 16 + lq * 4 + rr;
        float v = acc[mi][ni][rr] + bias;
        if (mode == 0) {
          int m = r >> 10, t = r & 1023;
          int tu = d ? (1023 - t) : t;
          ((u16*)outv)[((size_t)((d * 1024 + tu) * 64 + m)) * 512 + n] = f2bf(v);
        } else {
          int t = r >> 6, m = r & 63;
          ((float*)outv)[((size_t)m * 1024 + t) * 1024 + d * 512 + n] = v;
        }
      }
    }
  }
}

// ---------------------------------------------------------------------------
// Recurrence: 128 blocks x 64 threads (1 wave each; trivially co-resident).
// bid = p*8 + G; G=(d*4+g) is the sync group (16 waves, one per 32-col chunk
// p). Whhb[32x512] slice per wave. UH[d][t][m][n]: read own U slice, then
// overwrite the same elements with h_t (as packed u32 atomic stores).
//
// Writer pack: lane l=lq*16+lr holds c0[rr] (col p*32+lr) and c1[rr]
// (col p*32+16+lr) of row g*16+lq*4+rr. Adjacent cols live in adjacent
// lanes, so one __shfl_xor(v,1) + pack yields one u32 (2 bf16) per lane:
//   even lr: word (p*16 + lr/2)      = pack(v0_own, v0_partner)
//   odd  lr: word (p*16 + 8 + lr/2)  = pack(v1_partner, v1_own)
// Reader: frag a[ks] = rows lr, cols ks*32+lq*8.. -> 2 relaxed atomic u64
// loads. All racing accesses are relaxed agent atomics -> fence-free.
// ---------------------------------------------------------------------------
__global__ __launch_bounds__(64, 1) void rnn_kernel(
    const u16* __restrict__ h0b,
    const u16* __restrict__ Whh0, const u16* __restrict__ Whh1,
    u16* __restrict__ UH, float* __restrict__ tail, int* __restrict__ flags)
{
  int bid = blockIdx.x;
  int G = bid & 7;
  int p = bid >> 3;
  int d = G >> 2, g = G & 3;
  int l = threadIdx.x;
  int lr = l & 15, lq = l >> 4;

  const u16* Whh = d ? Whh1 : Whh0;

  // B-frags: n = p*32 + tl*16 + lr ; k = ks*32 + lq*8  (B[k][n] = Whh[n][k])
  frag8 Bf[2][16];
  #pragma unroll
  for (int tl = 0; tl < 2; ++tl)
    #pragma unroll
    for (int ks = 0; ks < 16; ++ks)
      Bf[tl][ks] = *(const frag8*)(Whh + (size_t)(p * 32 + tl * 16 + lr) * 512 + ks * 32 + lq * 8);

  int* myflag = flags + (G * 16 + p) * 32;             // 128B-spaced lines
  const int* pollp = flags + (G * 16 + (l & 15)) * 32; // lane i polls flag i

  // t=0 A-frag source (plain: written by a prior kernel, boundary-coherent)
  const u16* h0p = h0b + (size_t)(d * 64 + g * 16 + lr) * 512 + lq * 8;
  // A-frag atomic u64 view: row (d*65536 + t*64 + g*16 + lr), 128 u64/row
  const u64* HbQ = (const u64*)UH + ((size_t)d * 65536 + (size_t)(g * 16 + lr)) * 128 + lq * 2;
  // own-U prefetch (u16 view): rows lq*4+rr, cols p*32+lr / +16
  const u16* Up = UH + ((size_t)d * 65536 + (size_t)(g * 16 + lq * 4)) * 512 + p * 32 + lr;
  // h-write u32 view: word index per pack rule above
  int widx = (lr & 1) ? (p * 16 + 8 + (lr >> 1)) : (p * 16 + (lr >> 1));
  u32* Wp0 = (u32*)UH + ((size_t)d * 65536 + (size_t)(g * 16 + lq * 4)) * 256 + widx;

  for (int t = 0; t < 1024; ++t) {
    // Prefetch own U slice (only ever touched by this wave at step t ->
    // race-free plain cached loads; partner data in the same line is never
    // plain-read).
    float uv[2][4];
    {
      const u16* up = Up + (size_t)t * 32768;
      #pragma unroll
      for (int tl = 0; tl < 2; ++tl)
        #pragma unroll
        for (int rr = 0; rr < 4; ++rr)
          uv[tl][rr] = bf2f(up[(size_t)rr * 512 + tl * 16]);
    }
    if (t > 0) {
      // lane-parallel poll: one atomic load covers all 16 flags per round
      for (;;) {
        int v = __hip_atomic_load(pollp, __ATOMIC_RELAXED, __HIP_MEMORY_SCOPE_AGENT);
        if (__all(v >= t)) break;
        __builtin_amdgcn_s_sleep(1);
      }
      asm volatile("" ::: "memory");   // keep h-loads below the poll
    }
    f32x4 c0, c1;
    #pragma unroll
    for (int rr = 0; rr < 4; ++rr) { c0[rr] = uv[0][rr]; c1[rr] = uv[1][rr]; }

    // A-frags h_{t-1}: relaxed agent atomic u64 loads (fresh at the
    // coherence point; compiler emits the right cache bits and waitcnts).
    frag8 a[16];
    if (t == 0) {
      #pragma unroll
      for (int ks = 0; ks < 16; ++ks)
        a[ks] = *(const frag8*)(h0p + ks * 32);
    } else {
      const u64* q = HbQ + (size_t)(t - 1) * 8192;
      #pragma unroll
      for (int ks = 0; ks < 16; ++ks) {
        union { u64 u[2]; frag8 f; } cv;
        cv.u[0] = __hip_atomic_load(q + ks * 8,     __ATOMIC_RELAXED, __HIP_MEMORY_SCOPE_AGENT);
        cv.u[1] = __hip_atomic_load(q + ks * 8 + 1, __ATOMIC_RELAXED, __HIP_MEMORY_SCOPE_AGENT);
        a[ks] = cv.f;
      }
    }
    #pragma unroll
    for (int ks = 0; ks < 16; ++ks) {
      c0 = __builtin_amdgcn_mfma_f32_16x16x32_bf16(a[ks], Bf[0][ks], c0, 0, 0, 0);
      c1 = __builtin_amdgcn_mfma_f32_16x16x32_bf16(a[ks], Bf[1][ks], c1, 0, 0, 0);
    }

    // tanh + pack adjacent cols via lane-pair shuffle + atomic u32 publish
    u32* wp = Wp0 + (size_t)t * 16384;
    #pragma unroll
    for (int rr = 0; rr < 4; ++rr) {
      float v0 = tanh_fast(c0[rr]);
      float v1 = tanh_fast(c1[rr]);
      float q0 = __shfl_xor(v0, 1);
      float q1 = __shfl_xor(v1, 1);
      u32 Wd = (lr & 1)
             ? ((u32)f2bf(q1) | ((u32)f2bf(v1) << 16))
             : ((u32)f2bf(v0) | ((u32)f2bf(q0) << 16));
      __hip_atomic_store(wp + (size_t)rr * 256, Wd, __ATOMIC_RELAXED, __HIP_MEMORY_SCOPE_AGENT);
      if (t == 1023) {
        size_t tb = (size_t)(d * 64 + g * 16 + lq * 4 + rr) * 512 + p * 32 + lr;
        tail[tb]      = v0;
        tail[tb + 16] = v1;
      }
    }
    // release: store-ack at the coherence point, then flag. No cache
    // maintenance needed -- no racing data ever sits dirty in L1/L2.
    asm volatile("s_waitcnt vmcnt(0)" ::: "memory");
    if (l == 0)
      __hip_atomic_store(myflag, t + 1, __ATOMIC_RELAXED, __HIP_MEMORY_SCOPE_AGENT);
  }
}

// ---------------------------------------------------------------------------
extern "C" void kernel_launch(void* const* d_in, const int* in_sizes, int n_in,
                              void* d_out, int out_size, void* d_ws, size_t ws_size,
                              hipStream_t stream)
{
  const float* x     = (const float*)d_in[0];
  const float* h0    = (const float*)d_in[1];
  const float* fwWih = (const float*)d_in[2];
  const float* fwWhh = (const float*)d_in[3];
  const float* fwbih = (const float*)d_in[4];
  const float* fwbhh = (const float*)d_in[5];
  const float* fwfcW = (const float*)d_in[6];
  const float* fwfcb = (const float*)d_in[7];
  const float* bwWih = (const float*)d_in[8];
  const float* bwWhh = (const float*)d_in[9];
  const float* bwbih = (const float*)d_in[10];
  const float* bwbhh = (const float*)d_in[11];
  const float* bwfcW = (const float*)d_in[12];
  const float* bwfcb = (const float*)d_in[13];

  float* out = (float*)d_out;

  u16* UH    = (u16*)d_ws;
  u16* Xb    = UH + UTOT;
  u16* Wihb0 = Xb + SEQ;            // x is 33554432 elems
  u16* Wihb1 = Wihb0 + 262144;
  u16* Whhb0 = Wihb1 + 262144;
  u16* Whhb1 = Whhb0 + 262144;
  u16* fcWb0 = Whhb1 + 262144;
  u16* fcWb1 = fcWb0 + 262144;
  u16* h0b   = fcWb1 + 262144;

  // flags live in the Xb region: Xb is dead once phase-1 gemm has read it,
  // and the memset below is stream-ordered after that gemm.
  int* flags = (int*)Xb;            // 8 groups x 16 waves x 128B = 16 KiB

  // Phase 0: f32 -> bf16 conversions
  cvt_kernel<<<32768, 256, 0, stream>>>(x, Xb, 8388608);
  cvt_kernel<<<256, 256, 0, stream>>>(fwWih, Wihb0, 65536);
  cvt_kernel<<<256, 256, 0, stream>>>(bwWih, Wihb1, 65536);
  cvt_kernel<<<256, 256, 0, stream>>>(fwWhh, Whhb0, 65536);
  cvt_kernel<<<256, 256, 0, stream>>>(bwWhh, Whhb1, 65536);
  cvt_kernel<<<256, 256, 0, stream>>>(fwfcW, fcWb0, 65536);
  cvt_kernel<<<256, 256, 0, stream>>>(bwfcW, fcWb1, 65536);
  cvt_kernel<<<64, 256, 0, stream>>>(h0, h0b, 16384);

  // Phase 1: UH = xb @ Wihb^T + (bih+bhh), both dirs (bw time-flip at store)
  gemm_kernel<<<4096, 256, 0, stream>>>(Xb, Xb, Wihb0, Wihb1,
                                        fwbih, fwbhh, bwbih, bwbhh, UH, 0);

  // zero flags (after phase-1 gemm is done with Xb)
  hipMemsetAsync(flags, 0, 16384, stream);

  // Phase 2: recurrence, h stored in place into UH
  rnn_kernel<<<128, 64, 0, stream>>>(h0b, Whhb0, Whhb1, UH,
                                     out + 67108864ull, flags);

  // Phase 3: y = UH @ fcWb^T + fcb  (f32 output)
  gemm_kernel<<<4096, 256, 0, stream>>>(UH, UH + SEQ, fcWb0, fcWb1,
                                        fwfcb, nullptr, bwfcb, nullptr, out, 1);
}